// Round 3
// baseline (1641.915 us; speedup 1.0000x reference)
//
#include <hip/hip_runtime.h>

typedef unsigned long long ull;
typedef __bf16 bf16x8 __attribute__((ext_vector_type(8)));
typedef float f32x4 __attribute__((ext_vector_type(4)));

__device__ __forceinline__ float bf2f(unsigned short u) {
  union { unsigned int i; float f; } c; c.i = ((unsigned int)u) << 16; return c.f;
}
__device__ __forceinline__ unsigned short f2bf(float f) {
  union { float f; unsigned int i; } c; c.f = f;
  unsigned int u = c.i;
  u += 0x7fffu + ((u >> 16) & 1u);
  return (unsigned short)(u >> 16);
}

// ---- pack 4x [256,K] fp32 weights -> bf16 [1024,K] + bias concat ----------
__global__ __launch_bounds__(256) void pack_weights(
    const float* __restrict__ wq, const float* __restrict__ wk,
    const float* __restrict__ wv, const float* __restrict__ ws,
    const float* __restrict__ bq, const float* __restrict__ bk,
    const float* __restrict__ bv, const float* __restrict__ bs,
    unsigned short* __restrict__ Wcat, float* __restrict__ bcat, int logK) {
  int idx = blockIdx.x * 256 + threadIdx.x;
  if (idx < 1024) {
    int rr = idx >> 8, cc = idx & 255;
    const float* bp = (rr == 0) ? bq : (rr == 1) ? bk : (rr == 2) ? bv : bs;
    bcat[idx] = bp[cc];
  }
  int K = 1 << logK;
  if (idx >= (1024 << logK)) return;
  int o = idx >> logK, k = idx & (K - 1);
  int rr = o >> 8, oo = o & 255;
  const float* wp = (rr == 0) ? wq : (rr == 1) ? wk : (rr == 2) ? wv : ws;
  Wcat[idx] = f2bf(wp[oo * K + k]);
}

// ---- embedding gather: x[n, f*64+j] = emb[x_idx[n,f], j], fp32 -> bf16 ----
__global__ __launch_bounds__(256) void embed_gather(
    const int* __restrict__ x_idx, const float* __restrict__ emb,
    unsigned short* __restrict__ xbf, int total) {
  int idx = blockIdx.x * 256 + threadIdx.x;
  if (idx >= total) return;
  int node = idx >> 9, d = idx & 511, f = d >> 6, j = d & 63;
  int vi = x_idx[node * 8 + f];
  xbf[idx] = f2bf(emb[vi * 64 + j]);
}

// ---- CSR build ------------------------------------------------------------
__global__ __launch_bounds__(256) void count_dst(const int* __restrict__ dst,
                                                 int* __restrict__ counts, int E_) {
  int i = blockIdx.x * 256 + threadIdx.x;
  if (i < E_) atomicAdd(&counts[dst[i]], 1);
}

__global__ __launch_bounds__(256) void alloc_rows(const int* __restrict__ counts,
                                                  int* __restrict__ row_start,
                                                  int* __restrict__ cursor,
                                                  int* __restrict__ total, int n) {
  int i = blockIdx.x * 256 + threadIdx.x;
  int lane = threadIdx.x & 63;
  int c = (i < n) ? counts[i] : 0;
  int incl = c;
#pragma unroll
  for (int off = 1; off < 64; off <<= 1) {
    int t = __shfl_up(incl, off, 64);
    if (lane >= off) incl += t;
  }
  int base = 0;
  if (lane == 63) base = atomicAdd(total, incl);
  base = __shfl(base, 63, 64);
  int st = base + incl - c;
  if (i < n) { row_start[i] = st; cursor[i] = st; }
}

// scatter edges into CSR order; materialize permuted src/dst ids and attrs
__global__ __launch_bounds__(256) void scatter_edges(
    const int* __restrict__ dst, const int* __restrict__ srcA,
    const float* __restrict__ eattr, int* __restrict__ cursor,
    int* __restrict__ srcs, int* __restrict__ dsts,
    float* __restrict__ ea_perm, int E_) {
  int i = blockIdx.x * 256 + threadIdx.x;
  if (i >= E_) return;
  int d = dst[i];
  int p = atomicAdd(&cursor[d], 1);
  srcs[p] = srcA[i];
  dsts[p] = d;
  const float* ea = eattr + (size_t)i * 6;
  float* eo = ea_perm + (size_t)p * 6;
  eo[0] = ea[0]; eo[1] = ea[1]; eo[2] = ea[2];
  eo[3] = ea[3]; eo[4] = ea[4]; eo[5] = ea[5];
}

// ---- fused QKVS GEMM: [N,K]bf16 x [1024,K]bf16 -> q,k,v bf16 + skip fp32 --
// q pre-scaled by 1/16 (1/sqrt(DH)).
template <int K>
__global__ __launch_bounds__(256) void gemm_qkvs(
    const unsigned short* __restrict__ X, const unsigned short* __restrict__ W,
    const float* __restrict__ bcat,
    unsigned short* __restrict__ qout, unsigned short* __restrict__ kout,
    unsigned short* __restrict__ vout, float* __restrict__ sout, int Nn) {
  const int wid = threadIdx.x >> 6;
  const int lane = threadIdx.x & 63;
  const int quad = lane >> 4, lm = lane & 15;
  const int m_base = blockIdx.x * 128 + wid * 32;
  const int n_base = blockIdx.y * 64;
  const int r0 = min(m_base + lm, Nn - 1);
  const int r1 = min(m_base + 16 + lm, Nn - 1);
  const bf16x8* a0p = (const bf16x8*)(X + (size_t)r0 * K + quad * 8);
  const bf16x8* a1p = (const bf16x8*)(X + (size_t)r1 * K + quad * 8);
  const bf16x8* b0p = (const bf16x8*)(W + (size_t)(n_base + lm) * K + quad * 8);
  const bf16x8* b1p = (const bf16x8*)(W + (size_t)(n_base + 16 + lm) * K + quad * 8);
  const bf16x8* b2p = (const bf16x8*)(W + (size_t)(n_base + 32 + lm) * K + quad * 8);
  const bf16x8* b3p = (const bf16x8*)(W + (size_t)(n_base + 48 + lm) * K + quad * 8);
  f32x4 acc[2][4] = {};
#pragma unroll 4
  for (int k0 = 0; k0 < K; k0 += 32) {
    const int ko = k0 >> 3;  // 32 shorts = 4 bf16x8 units
    bf16x8 a0 = a0p[ko], a1 = a1p[ko];
    bf16x8 b0 = b0p[ko], b1 = b1p[ko], b2 = b2p[ko], b3 = b3p[ko];
    acc[0][0] = __builtin_amdgcn_mfma_f32_16x16x32_bf16(a0, b0, acc[0][0], 0, 0, 0);
    acc[0][1] = __builtin_amdgcn_mfma_f32_16x16x32_bf16(a0, b1, acc[0][1], 0, 0, 0);
    acc[0][2] = __builtin_amdgcn_mfma_f32_16x16x32_bf16(a0, b2, acc[0][2], 0, 0, 0);
    acc[0][3] = __builtin_amdgcn_mfma_f32_16x16x32_bf16(a0, b3, acc[0][3], 0, 0, 0);
    acc[1][0] = __builtin_amdgcn_mfma_f32_16x16x32_bf16(a1, b0, acc[1][0], 0, 0, 0);
    acc[1][1] = __builtin_amdgcn_mfma_f32_16x16x32_bf16(a1, b1, acc[1][1], 0, 0, 0);
    acc[1][2] = __builtin_amdgcn_mfma_f32_16x16x32_bf16(a1, b2, acc[1][2], 0, 0, 0);
    acc[1][3] = __builtin_amdgcn_mfma_f32_16x16x32_bf16(a1, b3, acc[1][3], 0, 0, 0);
  }
#pragma unroll
  for (int mi = 0; mi < 2; mi++) {
#pragma unroll
    for (int r = 0; r < 4; r++) {
      int row = m_base + mi * 16 + quad * 4 + r;
      if (row >= Nn) continue;
      size_t rb = (size_t)row * 256;
#pragma unroll
      for (int ni = 0; ni < 4; ni++) {
        int col = n_base + ni * 16 + lm;
        float v = acc[mi][ni][r] + bcat[col];
        int reg = col >> 8, c = col & 255;
        if (reg == 0)       qout[rb + c] = f2bf(v * 0.0625f);
        else if (reg == 1)  kout[rb + c] = f2bf(v);
        else if (reg == 2)  vout[rb + c] = f2bf(v);
        else                sout[rb + c] = v;
      }
    }
  }
}

// ---- node_prep: z[n] = We^T q[n] (6), c[n] = q[n].be -> zc[n][8] ----------
__global__ __launch_bounds__(256) void node_prep(
    const unsigned short* __restrict__ qv,
    const float* __restrict__ we, const float* __restrict__ be,
    float* __restrict__ zc, int Nn) {
  __shared__ float we_s[1536];
  __shared__ float be_s[256];
  for (int i = threadIdx.x; i < 1536; i += 256) we_s[i] = we[i];
  be_s[threadIdx.x] = be[threadIdx.x];
  __syncthreads();
  int wid = threadIdx.x >> 6, lane = threadIdx.x & 63;
  int n = blockIdx.x * 4 + wid;
  if (n >= Nn) return;
  int j0 = lane * 4;
  ull uq = *(const ull*)(qv + (size_t)n * 256 + j0);
  float q0 = bf2f((unsigned short)uq), q1 = bf2f((unsigned short)(uq >> 16));
  float q2 = bf2f((unsigned short)(uq >> 32)), q3 = bf2f((unsigned short)(uq >> 48));
  float part[7];
#pragma unroll
  for (int t = 0; t < 6; t++) {
    part[t] = we_s[(j0 + 0) * 6 + t] * q0 + we_s[(j0 + 1) * 6 + t] * q1
            + we_s[(j0 + 2) * 6 + t] * q2 + we_s[(j0 + 3) * 6 + t] * q3;
  }
  part[6] = be_s[j0] * q0 + be_s[j0 + 1] * q1 + be_s[j0 + 2] * q2 + be_s[j0 + 3] * q3;
#pragma unroll
  for (int off = 32; off > 0; off >>= 1) {
#pragma unroll
    for (int t = 0; t < 7; t++) part[t] += __shfl_xor(part[t], off, 64);
  }
  if (lane == 0) {
    float* zp = zc + (size_t)n * 8;
#pragma unroll
    for (int t = 0; t < 7; t++) zp[t] = part[t];
    zp[7] = 0.f;
  }
}

__device__ __forceinline__ float dot4(ull uq, ull uk) {
  return bf2f((unsigned short)uq) * bf2f((unsigned short)uk)
       + bf2f((unsigned short)(uq >> 16)) * bf2f((unsigned short)(uk >> 16))
       + bf2f((unsigned short)(uq >> 32)) * bf2f((unsigned short)(uk >> 32))
       + bf2f((unsigned short)(uq >> 48)) * bf2f((unsigned short)(uk >> 48));
}

// ---- P1: edge-parallel logits = q[dst].k[src] + z[dst].u + c[dst] ---------
__global__ __launch_bounds__(256) void edge_logits(
    const int* __restrict__ srcs, const int* __restrict__ dsts,
    const float* __restrict__ ea_perm,
    const unsigned short* __restrict__ qv, const unsigned short* __restrict__ kv,
    const float* __restrict__ zc, int E_, float* __restrict__ logits) {
  int wid = threadIdx.x >> 6, lane = threadIdx.x & 63;
  int p0 = (blockIdx.x * 4 + wid) * 4;
  if (p0 >= E_) return;
  int pe = min(4, E_ - p0);
  int j0 = lane * 4;
  int s[4], d[4];
#pragma unroll
  for (int t = 0; t < 4; t++) {
    int pp = p0 + ((t < pe) ? t : (pe - 1));
    s[t] = srcs[pp];
    d[t] = dsts[pp];
  }
  ull uk[4], uq[4];
#pragma unroll
  for (int t = 0; t < 4; t++) uk[t] = *(const ull*)(kv + (size_t)s[t] * 256 + j0);
#pragma unroll
  for (int t = 0; t < 4; t++) uq[t] = *(const ull*)(qv + (size_t)d[t] * 256 + j0);
  float pv[4];
#pragma unroll
  for (int t = 0; t < 4; t++) pv[t] = dot4(uq[t], uk[t]);
#pragma unroll
  for (int off = 32; off > 0; off >>= 1) {
    pv[0] += __shfl_xor(pv[0], off, 64);
    pv[1] += __shfl_xor(pv[1], off, 64);
    pv[2] += __shfl_xor(pv[2], off, 64);
    pv[3] += __shfl_xor(pv[3], off, 64);
  }
  if (lane == 0) {
    for (int t = 0; t < pe; t++) {
      const float* zp = zc + (size_t)d[t] * 8;
      const float* u = ea_perm + (size_t)(p0 + t) * 6;
      float zd = zp[0] * u[0] + zp[1] * u[1] + zp[2] * u[2]
               + zp[3] * u[3] + zp[4] * u[4] + zp[5] * u[5] + zp[6];
      logits[p0 + t] = pv[t] + zd;
    }
  }
}

// ---- P2: per-node softmax; overwrite logits with final weights ------------
__global__ __launch_bounds__(256) void node_softmax(
    const int* __restrict__ row_start, const int* __restrict__ counts,
    float* __restrict__ logits, int Nn) {
  int wid = threadIdx.x >> 6, lane = threadIdx.x & 63;
  int n = blockIdx.x * 4 + wid;
  if (n >= Nn) return;
  int beg = row_start[n], cnt = counts[n];
  if (cnt == 0) return;
  float lm = -INFINITY;
  for (int b = lane; b < cnt; b += 64) lm = fmaxf(lm, logits[beg + b]);
#pragma unroll
  for (int off = 32; off > 0; off >>= 1) lm = fmaxf(lm, __shfl_xor(lm, off, 64));
  float se = 0.f;
  for (int b = lane; b < cnt; b += 64) se += __expf(logits[beg + b] - lm);
#pragma unroll
  for (int off = 32; off > 0; off >>= 1) se += __shfl_xor(se, off, 64);
  float inv = 1.f / se;
  for (int b = lane; b < cnt; b += 64) {
    int p = beg + b;
    logits[p] = __expf(logits[p] - lm) * inv;
  }
}

// ---- P3: node-parallel weighted v-gather-sum + edge-MLP epilogue ----------
// agg = sum w*v[src] + We*(sum w*u) + be  (sum w == 1). No carried chains:
// every iteration independent -> deep load pipelining.
// mode 0: write h bf16. mode 1: fused pooling.
__global__ __launch_bounds__(256) void node_vagg(
    const int* __restrict__ srcs, const float* __restrict__ ea_perm,
    const float* __restrict__ wgt,
    const int* __restrict__ row_start, const int* __restrict__ counts,
    const unsigned short* __restrict__ vv, const float* __restrict__ skipv,
    const float* __restrict__ we, const float* __restrict__ be,
    int Nn, int mode,
    unsigned short* __restrict__ hout,
    const int* __restrict__ batch, float* __restrict__ gap,
    unsigned int* __restrict__ gmp) {
  __shared__ float we_s[1536];
  __shared__ float be_s[256];
  for (int i = threadIdx.x; i < 1536; i += 256) we_s[i] = we[i];
  be_s[threadIdx.x] = be[threadIdx.x];
  __syncthreads();
  int wid = threadIdx.x >> 6, lane = threadIdx.x & 63;
  int n = blockIdx.x * 4 + wid;
  if (n >= Nn) return;
  int j0 = lane * 4;
  int beg = row_start[n], cnt = counts[n];
  float a0 = 0.f, a1 = 0.f, a2 = 0.f, a3 = 0.f;
  float ub0 = 0.f, ub1 = 0.f, ub2 = 0.f, ub3 = 0.f, ub4 = 0.f, ub5 = 0.f;
  for (int i = 0; i < cnt; i += 4) {
    bool c1 = (i + 1 < cnt), c2 = (i + 2 < cnt), c3 = (i + 3 < cnt);
    int p0 = beg + i;
    int p1 = p0 + (c1 ? 1 : 0), p2 = p0 + (c2 ? 2 : 0), p3 = p0 + (c3 ? 3 : 0);
    float w0 = wgt[p0];
    float w1 = c1 ? wgt[p1] : 0.f;
    float w2 = c2 ? wgt[p2] : 0.f;
    float w3 = c3 ? wgt[p3] : 0.f;
    int s0 = srcs[p0], s1 = srcs[p1], s2 = srcs[p2], s3 = srcs[p3];
    ull uv0 = *(const ull*)(vv + (size_t)s0 * 256 + j0);
    ull uv1 = *(const ull*)(vv + (size_t)s1 * 256 + j0);
    ull uv2 = *(const ull*)(vv + (size_t)s2 * 256 + j0);
    ull uv3 = *(const ull*)(vv + (size_t)s3 * 256 + j0);
    const float* u0 = ea_perm + (size_t)p0 * 6;
    const float* u1 = ea_perm + (size_t)p1 * 6;
    const float* u2 = ea_perm + (size_t)p2 * 6;
    const float* u3 = ea_perm + (size_t)p3 * 6;
    a0 += w0 * bf2f((unsigned short)uv0) + w1 * bf2f((unsigned short)uv1)
        + w2 * bf2f((unsigned short)uv2) + w3 * bf2f((unsigned short)uv3);
    a1 += w0 * bf2f((unsigned short)(uv0 >> 16)) + w1 * bf2f((unsigned short)(uv1 >> 16))
        + w2 * bf2f((unsigned short)(uv2 >> 16)) + w3 * bf2f((unsigned short)(uv3 >> 16));
    a2 += w0 * bf2f((unsigned short)(uv0 >> 32)) + w1 * bf2f((unsigned short)(uv1 >> 32))
        + w2 * bf2f((unsigned short)(uv2 >> 32)) + w3 * bf2f((unsigned short)(uv3 >> 32));
    a3 += w0 * bf2f((unsigned short)(uv0 >> 48)) + w1 * bf2f((unsigned short)(uv1 >> 48))
        + w2 * bf2f((unsigned short)(uv2 >> 48)) + w3 * bf2f((unsigned short)(uv3 >> 48));
    ub0 += w0 * u0[0] + w1 * u1[0] + w2 * u2[0] + w3 * u3[0];
    ub1 += w0 * u0[1] + w1 * u1[1] + w2 * u2[1] + w3 * u3[1];
    ub2 += w0 * u0[2] + w1 * u1[2] + w2 * u2[2] + w3 * u3[2];
    ub3 += w0 * u0[3] + w1 * u1[3] + w2 * u2[3] + w3 * u3[3];
    ub4 += w0 * u0[4] + w1 * u1[4] + w2 * u2[4] + w3 * u3[4];
    ub5 += w0 * u0[5] + w1 * u1[5] + w2 * u2[5] + w3 * u3[5];
  }
  float bsc = (cnt > 0) ? 1.f : 0.f;
  float e[4];
#pragma unroll
  for (int r = 0; r < 4; r++) {
    int d = j0 + r;
    e[r] = bsc * be_s[d]
         + we_s[d * 6 + 0] * ub0 + we_s[d * 6 + 1] * ub1 + we_s[d * 6 + 2] * ub2
         + we_s[d * 6 + 3] * ub3 + we_s[d * 6 + 4] * ub4 + we_s[d * 6 + 5] * ub5;
  }
  float4 skv = *(const float4*)(skipv + (size_t)n * 256 + j0);
  float h0 = fmaxf(a0 + e[0] + skv.x, 0.f);
  float h1 = fmaxf(a1 + e[1] + skv.y, 0.f);
  float h2 = fmaxf(a2 + e[2] + skv.z, 0.f);
  float h3 = fmaxf(a3 + e[3] + skv.w, 0.f);
  if (mode == 0) {
    ull hv = (ull)f2bf(h0) | ((ull)f2bf(h1) << 16) | ((ull)f2bf(h2) << 32) | ((ull)f2bf(h3) << 48);
    *(ull*)(hout + (size_t)n * 256 + j0) = hv;
  } else {
    int g = batch[n];
    size_t gb = (size_t)g * 256 + j0;
    atomicAdd(&gap[gb + 0], h0); atomicMax(&gmp[gb + 0], __float_as_uint(h0));
    atomicAdd(&gap[gb + 1], h1); atomicMax(&gmp[gb + 1], __float_as_uint(h1));
    atomicAdd(&gap[gb + 2], h2); atomicMax(&gmp[gb + 2], __float_as_uint(h2));
    atomicAdd(&gap[gb + 3], h3); atomicMax(&gmp[gb + 3], __float_as_uint(h3));
  }
}

// ---- per-graph pooling finalize + 3-layer MLP + sigmoid -------------------
__global__ __launch_bounds__(256) void pool_mlp(
    const float* __restrict__ gap, const unsigned int* __restrict__ gmp,
    const int* __restrict__ batch, int Nn,
    const float* __restrict__ w1, const float* __restrict__ b1,
    const float* __restrict__ w2, const float* __restrict__ b2,
    const float* __restrict__ w3, const float* __restrict__ b3,
    float* __restrict__ out) {
  int g = blockIdx.x, t = threadIdx.x;
  __shared__ float r[512];
  __shared__ float o1[256];
  __shared__ float o2[128];
  __shared__ float red[256];
  __shared__ int cnt_s;
  if (t == 0) {
    int lo = 0, hi = Nn;
    while (lo < hi) { int mid = (lo + hi) >> 1; if (batch[mid] < g) lo = mid + 1; else hi = mid; }
    int st = lo;
    lo = 0; hi = Nn;
    while (lo < hi) { int mid = (lo + hi) >> 1; if (batch[mid] < g + 1) lo = mid + 1; else hi = mid; }
    cnt_s = lo - st;
  }
  __syncthreads();
  float inv = 1.f / fmaxf((float)cnt_s, 1.f);
  r[t] = gap[(size_t)g * 256 + t] * inv;
  r[256 + t] = __uint_as_float(gmp[(size_t)g * 256 + t]);
  __syncthreads();
  {
    float a = b1[t];
    const float* wr = w1 + (size_t)t * 512;
    for (int k = 0; k < 512; k++) a += wr[k] * r[k];
    o1[t] = fmaxf(a, 0.f);
  }
  __syncthreads();
  if (t < 128) {
    float a = b2[t];
    const float* wr = w2 + (size_t)t * 256;
    for (int k = 0; k < 256; k++) a += wr[k] * o1[k];
    o2[t] = fmaxf(a, 0.f);
  }
  __syncthreads();
  red[t] = (t < 128) ? w3[t] * o2[t] : 0.f;
  __syncthreads();
  for (int s = 128; s > 0; s >>= 1) {
    if (t < s) red[t] += red[t + s];
    __syncthreads();
  }
  if (t == 0) out[g] = 1.f / (1.f + expf(-(red[0] + b3[0])));
}

// ---------------------------------------------------------------------------
extern "C" void kernel_launch(void* const* d_in, const int* in_sizes, int n_in,
                              void* d_out, int out_size, void* d_ws, size_t ws_size,
                              hipStream_t stream) {
  const int* x_idx      = (const int*)d_in[0];
  const int* edge_index = (const int*)d_in[1];
  const float* eattr    = (const float*)d_in[2];
  const int* batch      = (const int*)d_in[3];
  const float* emb      = (const float*)d_in[4];
  const float* c1_wq = (const float*)d_in[5],  *c1_bq = (const float*)d_in[6];
  const float* c1_wk = (const float*)d_in[7],  *c1_bk = (const float*)d_in[8];
  const float* c1_wv = (const float*)d_in[9],  *c1_bv = (const float*)d_in[10];
  const float* c1_we = (const float*)d_in[11], *c1_be = (const float*)d_in[12];
  const float* c1_ws = (const float*)d_in[13], *c1_bs = (const float*)d_in[14];
  const float* c2_wq = (const float*)d_in[15], *c2_bq = (const float*)d_in[16];
  const float* c2_wk = (const float*)d_in[17], *c2_bk = (const float*)d_in[18];
  const float* c2_wv = (const float*)d_in[19], *c2_bv = (const float*)d_in[20];
  const float* c2_we = (const float*)d_in[21], *c2_be = (const float*)d_in[22];
  const float* c2_ws = (const float*)d_in[23], *c2_bs = (const float*)d_in[24];
  const float* w1 = (const float*)d_in[25], *b1 = (const float*)d_in[26];
  const float* w2 = (const float*)d_in[27], *b2 = (const float*)d_in[28];
  const float* w3 = (const float*)d_in[29], *b3 = (const float*)d_in[30];

  const int Nn = in_sizes[3];        // 50000
  const int Ee = in_sizes[1] / 2;    // 300000

  char* ws = (char*)d_ws;
  size_t off = 0;
  auto alloc = [&](size_t bytes) -> void* {
    void* p = ws + off;
    off += (bytes + 255) & ~(size_t)255;
    return p;
  };
  unsigned short* xbf   = (unsigned short*)alloc((size_t)Nn * 512 * 2);
  unsigned short* qbf   = (unsigned short*)alloc((size_t)Nn * 256 * 2);
  unsigned short* kbf   = (unsigned short*)alloc((size_t)Nn * 256 * 2);
  unsigned short* vbf   = (unsigned short*)alloc((size_t)Nn * 256 * 2);
  float*          skipf = (float*)alloc((size_t)Nn * 256 * 4);
  unsigned short* h1bf  = (unsigned short*)alloc((size_t)Nn * 256 * 2);
  unsigned short* Wcat1 = (unsigned short*)alloc((size_t)1024 * 512 * 2);
  float*          bcat1 = (float*)alloc(1024 * 4);
  unsigned short* Wcat2 = (unsigned short*)alloc((size_t)1024 * 256 * 2);
  float*          bcat2 = (float*)alloc(1024 * 4);
  int*            counts    = (int*)alloc((size_t)Nn * 4);
  int*            row_start = (int*)alloc((size_t)Nn * 4);
  int*            cursor    = (int*)alloc((size_t)Nn * 4);
  int*            srcs      = (int*)alloc((size_t)Ee * 4);
  int*            dsts      = (int*)alloc((size_t)Ee * 4);
  float*          ea_perm   = (float*)alloc((size_t)Ee * 6 * 4);
  float*          logits    = (float*)alloc((size_t)Ee * 4);   // becomes weights
  float*          zc        = (float*)alloc((size_t)Nn * 8 * 4);
  int*            total     = (int*)alloc(256);
  float*          gap       = (float*)alloc((size_t)64 * 256 * 4);
  unsigned int*   gmp       = (unsigned int*)alloc((size_t)64 * 256 * 4);
  // total ~220 MB (R1-proven budget; the 307 MB msg buffer was the R2 crash)

  const int* srcA = edge_index;
  const int* dstA = edge_index + Ee;

  hipMemsetAsync(counts, 0, (size_t)Nn * 4, stream);
  hipMemsetAsync(total, 0, 4, stream);
  hipMemsetAsync(gap, 0, (size_t)64 * 256 * 4, stream);
  hipMemsetAsync(gmp, 0, (size_t)64 * 256 * 4, stream);

  pack_weights<<<(1024 * 512 + 255) / 256, 256, 0, stream>>>(
      c1_wq, c1_wk, c1_wv, c1_ws, c1_bq, c1_bk, c1_bv, c1_bs, Wcat1, bcat1, 9);
  pack_weights<<<(1024 * 256 + 255) / 256, 256, 0, stream>>>(
      c2_wq, c2_wk, c2_wv, c2_ws, c2_bq, c2_bk, c2_bv, c2_bs, Wcat2, bcat2, 8);
  embed_gather<<<((Nn * 512) + 255) / 256, 256, 0, stream>>>(x_idx, emb, xbf, Nn * 512);
  count_dst<<<(Ee + 255) / 256, 256, 0, stream>>>(dstA, counts, Ee);
  alloc_rows<<<(Nn + 255) / 256, 256, 0, stream>>>(counts, row_start, cursor, total, Nn);
  scatter_edges<<<(Ee + 255) / 256, 256, 0, stream>>>(dstA, srcA, eattr, cursor,
                                                      srcs, dsts, ea_perm, Ee);

  dim3 gg((Nn + 127) / 128, 16);
  const int egrid = (Ee + 15) / 16;   // 4 waves/block x 4 edges/wave
  const int ngrid = (Nn + 3) / 4;

  // layer 1
  gemm_qkvs<512><<<gg, 256, 0, stream>>>(xbf, Wcat1, bcat1, qbf, kbf, vbf, skipf, Nn);
  node_prep<<<ngrid, 256, 0, stream>>>(qbf, c1_we, c1_be, zc, Nn);
  edge_logits<<<egrid, 256, 0, stream>>>(srcs, dsts, ea_perm, qbf, kbf, zc, Ee, logits);
  node_softmax<<<ngrid, 256, 0, stream>>>(row_start, counts, logits, Nn);
  node_vagg<<<ngrid, 256, 0, stream>>>(srcs, ea_perm, logits, row_start, counts,
                                       vbf, skipf, c1_we, c1_be, Nn, 0,
                                       h1bf, nullptr, nullptr, nullptr);

  // layer 2
  gemm_qkvs<256><<<gg, 256, 0, stream>>>(h1bf, Wcat2, bcat2, qbf, kbf, vbf, skipf, Nn);
  node_prep<<<ngrid, 256, 0, stream>>>(qbf, c2_we, c2_be, zc, Nn);
  edge_logits<<<egrid, 256, 0, stream>>>(srcs, dsts, ea_perm, qbf, kbf, zc, Ee, logits);
  node_softmax<<<ngrid, 256, 0, stream>>>(row_start, counts, logits, Nn);
  node_vagg<<<ngrid, 256, 0, stream>>>(srcs, ea_perm, logits, row_start, counts,
                                       vbf, skipf, c2_we, c2_be, Nn, 1,
                                       nullptr, batch, gap, gmp);

  pool_mlp<<<64, 256, 0, stream>>>(gap, gmp, batch, Nn, w1, b1, w2, b2, w3, b3,
                                   (float*)d_out);
}